// Round 14
// baseline (495.234 us; speedup 1.0000x reference)
//
#include <hip/hip_runtime.h>
#include <math.h>

#define CI   700
#define TIN  300
#define DD   25
#define TOUT 276
#define BB   64
#define OINH 128
#define OEXC 256

#define TROWS 312
#define IPAD  704

typedef __attribute__((ext_vector_type(8))) short short8;
typedef __attribute__((ext_vector_type(4))) float f32x4;
typedef __attribute__((ext_vector_type(8))) unsigned short ushort8v;

static __device__ __forceinline__ unsigned short f2bf(float f) {
    unsigned int u = __float_as_uint(f);
    unsigned int r = (u + 0x7FFFu + ((u >> 16) & 1u)) >> 16;
    return (unsigned short)r;
}
static __device__ __forceinline__ float bf2f(unsigned short h) {
    return __uint_as_float(((unsigned int)h) << 16);
}
static __device__ __forceinline__ void gload_lds16(const void* g, void* l) {
    __builtin_amdgcn_global_load_lds(
        (const __attribute__((address_space(1))) unsigned int*)g,
        (__attribute__((address_space(3))) unsigned int*)l, 16, 0, 0);
}

// ---------------------------------------------------------------------------
__global__ void build_kt(const float* __restrict__ W, const float* __restrict__ P,
                         const float* __restrict__ SIG, float* __restrict__ kt, int O) {
    int n = blockIdx.x * 256 + threadIdx.x;
    if (n >= O * CI) return;
    int o = n % O, i = n / O;
    float w   = fabsf(W[o * CI + i]);
    float p   = fminf(fmaxf(P[o * CI + i], -12.f), 12.f) + 12.f;
    float sig = fabsf(SIG[o * CI + i]) + 0.27f;
    float inv = 1.f / sig;
    float g[DD]; float sum = 0.f;
#pragma unroll
    for (int d = 0; d < DD; ++d) {
        float e = ((float)d - p) * inv;
        g[d] = expf(-0.5f * e * e); sum += g[d];
    }
    float sc = w / (sum + 1e-7f);
#pragma unroll
    for (int d = 0; d < DD; ++d)
        kt[(i * DD + d) * O + o] = g[d] * sc;
}

// ---------------------------------------------------------------------------
__global__ void kexc_build(const float* __restrict__ W, const float* __restrict__ P,
                           const float* __restrict__ SIG, unsigned short* __restrict__ kb2) {
    int n = blockIdx.x * 256 + threadIdx.x;
    if (n >= OEXC * IPAD) return;
    int o = n / IPAD, ip = n % IPAD;
    if (ip >= CI) {
#pragma unroll
        for (int d = 0; d < DD; ++d)
            kb2[((size_t)d * OEXC + o) * IPAD + ip] = 0;
        return;
    }
    float w   = fabsf(W[o * CI + ip]);
    float p   = fminf(fmaxf(P[o * CI + ip], -12.f), 12.f) + 12.f;
    float sig = fabsf(SIG[o * CI + ip]) + 0.27f;
    float inv = 1.f / sig;
    float g[DD]; float sum = 0.f;
#pragma unroll
    for (int d = 0; d < DD; ++d) {
        float e = ((float)d - p) * inv;
        g[d] = expf(-0.5f * e * e); sum += g[d];
    }
    float sc = w / (sum + 1e-7f);
#pragma unroll
    for (int d = 0; d < DD; ++d)
        kb2[((size_t)d * OEXC + o) * IPAD + ip] = f2bf(g[d] * sc);
}

// ---------------------------------------------------------------------------
__global__ void kinh_build(const float* __restrict__ W, const float* __restrict__ P,
                           const float* __restrict__ SIG,
                           unsigned short* __restrict__ kbh, unsigned short* __restrict__ kbl) {
    int n = blockIdx.x * 256 + threadIdx.x;
    if (n >= OINH * IPAD) return;
    int o = n / IPAD, ip = n % IPAD;
    if (ip >= CI) {
#pragma unroll
        for (int d = 0; d < DD; ++d) {
            kbh[((size_t)d * OINH + o) * IPAD + ip] = 0;
            kbl[((size_t)d * OINH + o) * IPAD + ip] = 0;
        }
        return;
    }
    float w   = fabsf(W[o * CI + ip]);
    float p   = fminf(fmaxf(P[o * CI + ip], -12.f), 12.f) + 12.f;
    float sig = fabsf(SIG[o * CI + ip]) + 0.27f;
    float inv = 1.f / sig;
    float g[DD]; float sum = 0.f;
#pragma unroll
    for (int d = 0; d < DD; ++d) {
        float e = ((float)d - p) * inv;
        g[d] = expf(-0.5f * e * e); sum += g[d];
    }
    float sc = w / (sum + 1e-7f);
#pragma unroll
    for (int d = 0; d < DD; ++d) {
        float v = g[d] * sc;
        unsigned short h = f2bf(v);
        kbh[((size_t)d * OINH + o) * IPAD + ip] = h;
        kbl[((size_t)d * OINH + o) * IPAD + ip] = f2bf(v - bf2f(h));
    }
}

// ---------------------------------------------------------------------------
__global__ __launch_bounds__(256)
void xt_kernel(const float* __restrict__ x, unsigned short* __restrict__ xTh,
               unsigned short* __restrict__ xTl) {
    __shared__ float tile[64][65];
    const int tid = threadIdx.x;
    const int t0 = blockIdx.x * 64, i0 = blockIdx.y * 64, b = blockIdx.z;
#pragma unroll
    for (int s = 0; s < 16; ++s) {
        int f = s * 256 + tid;
        int tt = f & 63, ii = f >> 6;
        float v = 0.f;
        if (t0 + tt < TIN && i0 + ii < CI)
            v = x[((size_t)b * CI + i0 + ii) * TIN + t0 + tt];
        tile[tt][ii] = v;
    }
    __syncthreads();
#pragma unroll
    for (int s = 0; s < 2; ++s) {
        int f = s * 256 + tid;
        int tt = f >> 3, g = f & 7;
        if (t0 + tt < TROWS) {
            ushort8v vh, vl;
#pragma unroll
            for (int e = 0; e < 8; ++e) {
                float v = tile[tt][g * 8 + e];
                unsigned short h = f2bf(v);
                vh[e] = h;
                vl[e] = f2bf(v - bf2f(h));
            }
            size_t off = ((size_t)b * TROWS + t0 + tt) * IPAD + i0 + g * 8;
            *(ushort8v*)(xTh + off) = vh;
            if (xTl) *(ushort8v*)(xTl + off) = vl;
        }
    }
}

// ---------------------------------------------------------------------------
__global__ void wt_kernel(const float* __restrict__ w, float* __restrict__ wt) {
    int n = blockIdx.x * 256 + threadIdx.x;
    if (n >= OINH * OEXC) return;
    int o = n % OEXC, c = n / OEXC;
    wt[c * OEXC + o] = -fabsf(w[o * OINH + c]);
}

// ===========================================================================
// FUSED conv v8: batch-pair + 2-d-per-iteration k pipeline.
// grid (6, 4, 32), 256 thr = 4 waves (wb = wave>>1, wo = wave&1):
//   x: tt = x%3 (t0), ksp = x/3; y: 0,1 INH (o0=y*64), 2,3 EXC (o0=(y-2)*128)
//   z: batch pair; b = 2*bp + wb
// One vmcnt(0)+barrier per d-PAIR. d ascending -> bitwise-identical output.
// LDS 64 KB: exc x[2]@0(16K) + k@16384 (buf*2+wo)*8192+s*4096;
//            inh xh[2]@0, xl[2]@16384, k@32768 (buf*2+wo)*8192+s*4096
//            (s-slice = kh 2KB | kl 2KB).
// ===========================================================================
__global__ __launch_bounds__(256, 2)
void conv_fused_v8(const unsigned short* __restrict__ xTh, const unsigned short* __restrict__ xTl,
                   const unsigned short* __restrict__ kb2,
                   const unsigned short* __restrict__ kbh, const unsigned short* __restrict__ kbl,
                   float* __restrict__ pexc0, float* __restrict__ pexc1,
                   float* __restrict__ pinh0, float* __restrict__ pinh1) {
    __shared__ unsigned short lds[32768];          // 64 KB

    const int tid  = threadIdx.x;
    const int wave = tid >> 6;
    const int lane = tid & 63;
    const int wb   = wave >> 1;
    const int wo   = wave & 1;
    const int l15 = lane & 15, l4 = lane >> 4;
    const int tt   = blockIdx.x % 3;
    const int ksp  = blockIdx.x / 3;
    const int role = blockIdx.y;                   // 0,1 inh; 2,3 exc
    const int bp   = blockIdx.z;
    const int t0   = tt * 96;
    const int icb  = ksp * 11;

    const int ld_r = lane >> 2;
    const int ld_c = (((lane & 3) ^ ((lane >> 3) & 3)) << 4);
    const int SA   = (l15 >> 1) & 3;

    const size_t xstride = (size_t)IPAD * 2;
    const int b = 2 * bp + wb;

    if (role >= 2) {
        // ============================ EXC ============================
        const int o0w = (role - 2) * 128 + wo * 64;

        f32x4 acc[4][6];
#pragma unroll
        for (int i = 0; i < 4; ++i)
#pragma unroll
            for (int j = 0; j < 6; ++j) acc[i][j] = (f32x4)0.f;

        for (int c = 0; c < 11; ++c) {
            const size_t cb = (size_t)(icb + c) * 64;
            __syncthreads();
            // x windows for both batches: 16 issues over 4 waves
            for (int j = wave; j < 16; j += 4) {
                const int q = j >> 3, jj = j & 7;
                const char* xb = (const char*)xTh +
                    ((size_t)(2 * bp + q) * TROWS + t0) * xstride;
                gload_lds16(xb + (size_t)(16 * jj + ld_r) * xstride + cb + ld_c,
                            (char*)lds + q * 8192 + jj * 1024);
            }
            // k d=0,1 -> buf0 (own o-half; wb-partner duplicates)
#pragma unroll
            for (int s = 0; s < 2; ++s) {
                const char* kbase = (const char*)kb2 +
                    ((size_t)(s * OEXC) + o0w) * xstride + cb;
                char* kdst = (char*)lds + 16384 + wo * 8192 + s * 4096;
#pragma unroll
                for (int j = 0; j < 4; ++j)
                    gload_lds16(kbase + (size_t)(16 * j + ld_r) * xstride + ld_c,
                                kdst + j * 1024);
            }
            asm volatile("s_waitcnt vmcnt(0)" ::: "memory");
            __syncthreads();

            for (int it = 0; it <= 12; ++it) {
                const int d0 = 2 * it;
                const int nb = (it + 1) & 1;
#pragma unroll
                for (int s = 0; s < 2; ++s) {
                    const int dn = d0 + 2 + s;
                    if (dn < DD) {
                        const char* kbase = (const char*)kb2 +
                            ((size_t)(dn * OEXC) + o0w) * xstride + cb;
                        char* kdst = (char*)lds + 16384 + (nb * 2 + wo) * 8192 + s * 4096;
#pragma unroll
                        for (int j = 0; j < 4; ++j)
                            gload_lds16(kbase + (size_t)(16 * j + ld_r) * xstride + ld_c,
                                        kdst + j * 1024);
                    }
                }
#pragma unroll
                for (int s = 0; s < 2; ++s) {
                    const int d = d0 + s;
                    if (d < DD) {
                        const char* kp = (const char*)lds + 16384 +
                                         ((it & 1) * 2 + wo) * 8192 + s * 4096;
                        short8 A[4];
#pragma unroll
                        for (int i = 0; i < 4; ++i)
                            A[i] = *(const short8*)(kp + (i * 16 + l15) * 64 +
                                                    ((l4 ^ SA) << 4));
#pragma unroll
                        for (int j = 0; j < 6; ++j) {
                            const int tr = j * 16 + l15 + d;
                            short8 Bv = *(const short8*)((const char*)lds + wb * 8192 +
                                                         tr * 64 + ((l4 ^ ((tr >> 1) & 3)) << 4));
#pragma unroll
                            for (int i = 0; i < 4; ++i)
                                acc[i][j] = __builtin_amdgcn_mfma_f32_16x16x32_bf16(
                                    A[i], Bv, acc[i][j], 0, 0, 0);
                        }
                    }
                }
                asm volatile("s_waitcnt vmcnt(0)" ::: "memory");
                __syncthreads();
            }
        }
        float* dst = ksp ? pexc1 : pexc0;
#pragma unroll
        for (int i = 0; i < 4; ++i)
#pragma unroll
            for (int j = 0; j < 6; ++j) {
                const int t = t0 + j * 16 + l15;
                if (t < TOUT) {
                    float* op = dst + ((size_t)b * OEXC + o0w + i * 16 + l4 * 4) * TOUT + t;
#pragma unroll
                    for (int r = 0; r < 4; ++r) op[(size_t)r * TOUT] = acc[i][j][r];
                }
            }
    } else {
        // ============================ INH ============================
        const int o0w = role * 64 + wo * 32;

        f32x4 acc[2][6];
#pragma unroll
        for (int i = 0; i < 2; ++i)
#pragma unroll
            for (int j = 0; j < 6; ++j) acc[i][j] = (f32x4)0.f;

        for (int c = 0; c < 11; ++c) {
            const size_t cb = (size_t)(icb + c) * 64;
            __syncthreads();
            for (int j = wave; j < 16; j += 4) {
                const int q = j >> 3, jj = j & 7;
                const size_t rowoff = ((size_t)(2 * bp + q) * TROWS + t0) * xstride +
                                      (size_t)(16 * jj + ld_r) * xstride + cb + ld_c;
                gload_lds16((const char*)xTh + rowoff, (char*)lds + q * 8192 + jj * 1024);
                gload_lds16((const char*)xTl + rowoff, (char*)lds + 16384 + q * 8192 + jj * 1024);
            }
#pragma unroll
            for (int s = 0; s < 2; ++s) {
                const size_t ko = ((size_t)(s * OINH) + o0w) * xstride + cb;
                char* kdst = (char*)lds + 32768 + wo * 8192 + s * 4096;
#pragma unroll
                for (int j = 0; j < 2; ++j) {
                    gload_lds16((const char*)kbh + ko + (size_t)(16 * j + ld_r) * xstride + ld_c,
                                kdst + j * 1024);
                    gload_lds16((const char*)kbl + ko + (size_t)(16 * j + ld_r) * xstride + ld_c,
                                kdst + 2048 + j * 1024);
                }
            }
            asm volatile("s_waitcnt vmcnt(0)" ::: "memory");
            __syncthreads();

            for (int it = 0; it <= 12; ++it) {
                const int d0 = 2 * it;
                const int nb = (it + 1) & 1;
#pragma unroll
                for (int s = 0; s < 2; ++s) {
                    const int dn = d0 + 2 + s;
                    if (dn < DD) {
                        const size_t ko = ((size_t)(dn * OINH) + o0w) * xstride + cb;
                        char* kdst = (char*)lds + 32768 + (nb * 2 + wo) * 8192 + s * 4096;
#pragma unroll
                        for (int j = 0; j < 2; ++j) {
                            gload_lds16((const char*)kbh + ko +
                                            (size_t)(16 * j + ld_r) * xstride + ld_c,
                                        kdst + j * 1024);
                            gload_lds16((const char*)kbl + ko +
                                            (size_t)(16 * j + ld_r) * xstride + ld_c,
                                        kdst + 2048 + j * 1024);
                        }
                    }
                }
#pragma unroll
                for (int s = 0; s < 2; ++s) {
                    const int d = d0 + s;
                    if (d < DD) {
                        const char* kp = (const char*)lds + 32768 +
                                         ((it & 1) * 2 + wo) * 8192 + s * 4096;
                        short8 Ah[2], Al[2];
#pragma unroll
                        for (int i = 0; i < 2; ++i) {
                            Ah[i] = *(const short8*)(kp + (i * 16 + l15) * 64 +
                                                     ((l4 ^ SA) << 4));
                            Al[i] = *(const short8*)(kp + 2048 + (i * 16 + l15) * 64 +
                                                     ((l4 ^ SA) << 4));
                        }
#pragma unroll
                        for (int j = 0; j < 6; ++j) {
                            const int tr = j * 16 + l15 + d;
                            const int xo = tr * 64 + ((l4 ^ ((tr >> 1) & 3)) << 4);
                            short8 Bh = *(const short8*)((const char*)lds + wb * 8192 + xo);
                            short8 Bl = *(const short8*)((const char*)lds + 16384 + wb * 8192 + xo);
#pragma unroll
                            for (int i = 0; i < 2; ++i) {
                                acc[i][j] = __builtin_amdgcn_mfma_f32_16x16x32_bf16(
                                    Ah[i], Bh, acc[i][j], 0, 0, 0);
                                acc[i][j] = __builtin_amdgcn_mfma_f32_16x16x32_bf16(
                                    Ah[i], Bl, acc[i][j], 0, 0, 0);
                                acc[i][j] = __builtin_amdgcn_mfma_f32_16x16x32_bf16(
                                    Al[i], Bh, acc[i][j], 0, 0, 0);
                            }
                        }
                    }
                }
                asm volatile("s_waitcnt vmcnt(0)" ::: "memory");
                __syncthreads();
            }
        }
        float* dst = ksp ? pinh1 : pinh0;
#pragma unroll
        for (int i = 0; i < 2; ++i)
#pragma unroll
            for (int j = 0; j < 6; ++j) {
                const int t = t0 + j * 16 + l15;
                if (t < TOUT) {
                    float* op = dst + ((size_t)b * OINH + o0w + i * 16 + l4 * 4) * TOUT + t;
#pragma unroll
                    for (int r = 0; r < 4; ++r) op[(size_t)r * TOUT] = acc[i][j][r];
                }
            }
    }
}

// ---------------------------------------------------------------------------
__global__ void add_exc(const float* __restrict__ p1, float* __restrict__ out) {
    int n = blockIdx.x * 256 + threadIdx.x;
    float4 a = ((const float4*)out)[n];
    float4 v = ((const float4*)p1)[n];
    a.x += v.x; a.y += v.y; a.z += v.z; a.w += v.w;
    ((float4*)out)[n] = a;
}

// ---------------------------------------------------------------------------
__global__ void bn_stats2(float* __restrict__ cinh, const float* __restrict__ q1,
                          const float* __restrict__ gamma, const float* __restrict__ beta,
                          float* __restrict__ scale, float* __restrict__ shift) {
    const int c = blockIdx.x, tid = threadIdx.x;
    float sum = 0.f, sq = 0.f;
    for (int idx = tid; idx < BB * TOUT; idx += 256) {
        int b = idx / TOUT, t = idx - b * TOUT;
        size_t off = (size_t)(b * OINH + c) * TOUT + t;
        float v = cinh[off] + q1[off];
        cinh[off] = v;
        sum += v; sq += v * v;
    }
#pragma unroll
    for (int off = 32; off; off >>= 1) {
        sum += __shfl_down(sum, off);
        sq  += __shfl_down(sq, off);
    }
    __shared__ float ls[8];
    int wid = tid >> 6;
    if ((tid & 63) == 0) { ls[wid * 2] = sum; ls[wid * 2 + 1] = sq; }
    __syncthreads();
    if (tid == 0) {
        float S = 0.f, Q = 0.f;
#pragma unroll
        for (int wv = 0; wv < 4; ++wv) { S += ls[wv * 2]; Q += ls[wv * 2 + 1]; }
        const float n = (float)(BB * TOUT);
        float mean = S / n;
        float var  = Q / n - mean * mean;
        float rs   = 1.f / sqrtf(var + 1e-5f);
        float sc   = gamma[c] * rs;
        scale[c] = sc;
        shift[c] = beta[c] - mean * sc;
    }
}

// ---------------------------------------------------------------------------
__global__ __launch_bounds__(128)
void lif2(const float* __restrict__ cinh, const float* __restrict__ scale,
          const float* __restrict__ shift, unsigned char* __restrict__ spk) {
    __shared__ float tile[128 * 65];
    const int b = blockIdx.x, c = threadIdx.x;
    const float sc = scale[c], sh = shift[c];
    const float* base = cinh + (size_t)b * OINH * TOUT;
    float v = 0.f;
    for (int tc = 0; tc < TOUT; tc += 64) {
        const int len = (TOUT - tc < 64) ? (TOUT - tc) : 64;
        const int L4 = len >> 2;
        __syncthreads();
        for (int q = c; q < 128 * L4; q += 128) {
            int cc = q / L4, e = q - cc * L4;
            float4 vv = *(const float4*)(base + (size_t)cc * TOUT + tc + e * 4);
            float* dstp = &tile[cc * 65 + e * 4];
            dstp[0] = vv.x; dstp[1] = vv.y; dstp[2] = vv.z; dstp[3] = vv.w;
        }
        __syncthreads();
        for (int t2 = 0; t2 < len; ++t2) {
            float xin = tile[c * 65 + t2] * sc + sh;
            v = 0.5f * v + xin;
            bool s = (v >= 1.f);
            spk[((size_t)(tc + t2) * BB + b) * OINH + c] = s ? 1 : 0;
            v = s ? 0.f : v;
        }
    }
}

// ---------------------------------------------------------------------------
// Fallback kernels (round-4 proven versions).
// ---------------------------------------------------------------------------
__global__ __launch_bounds__(128)
void conv_mfma(const unsigned short* __restrict__ xTh, const unsigned short* __restrict__ kb2,
               float* __restrict__ out) {
    __shared__ unsigned short xs[120 * 64];
    __shared__ unsigned short ks[2][2][64 * 64];

    const int tid  = threadIdx.x;
    const int wave = tid >> 6;
    const int lane = tid & 63;
    const int l15 = lane & 15, l4 = lane >> 4, l7 = lane & 7;
    const int b  = blockIdx.z;
    const int t0 = blockIdx.x * 96;
    const int o0 = blockIdx.y * 128 + wave * 64;

    const int ld_row = lane >> 3;
    const int ld_swz = ((l7 ^ ld_row) << 4);

    f32x4 acc[4][6];
#pragma unroll
    for (int i = 0; i < 4; ++i)
#pragma unroll
        for (int j = 0; j < 6; ++j) acc[i][j] = (f32x4)0.f;

    const char* xrow0 = (const char*)xTh + ((size_t)b * TROWS + t0) * (IPAD * 2);

    for (int ic = 0; ic < 11; ++ic) {
        const int ic0 = ic * 64;
        __syncthreads();
        for (int j = wave; j < 15; j += 2)
            gload_lds16(xrow0 + (size_t)(8 * j + ld_row) * (IPAD * 2) + ic0 * 2 + ld_swz,
                        (char*)xs + j * 1024);
        {
            const char* ksrc = (const char*)kb2 + ((size_t)o0) * (IPAD * 2) + ic0 * 2;
            char* kdst = (char*)ks + (0 * 2 + wave) * 8192;
#pragma unroll
            for (int j = 0; j < 8; ++j)
                gload_lds16(ksrc + (size_t)(8 * j + ld_row) * (IPAD * 2) + ld_swz,
                            kdst + j * 1024);
        }
        asm volatile("s_waitcnt vmcnt(0)" ::: "memory");
        __syncthreads();

        for (int d = 0; d < DD; ++d) {
            const int cur = d & 1;
            if (d < DD - 1) {
                const char* ksrc = (const char*)kb2 +
                    ((size_t)(d + 1) * OEXC + o0) * (IPAD * 2) + ic0 * 2;
                char* kdst = (char*)ks + ((cur ^ 1) * 2 + wave) * 8192;
#pragma unroll
                for (int j = 0; j < 8; ++j)
                    gload_lds16(ksrc + (size_t)(8 * j + ld_row) * (IPAD * 2) + ld_swz,
                                kdst + j * 1024);
            }
            const char* kp = (const char*)ks + (cur * 2 + wave) * 8192;
#pragma unroll
            for (int ks2 = 0; ks2 < 2; ++ks2) {
                const int cg = ks2 * 4 + l4;
                short8 A[4];
#pragma unroll
                for (int i = 0; i < 4; ++i)
                    A[i] = *(const short8*)(kp + (i * 16 + l15) * 128 + ((cg ^ l7) << 4));
#pragma unroll
                for (int j = 0; j < 6; ++j) {
                    const int tr = j * 16 + l15 + d;
                    short8 Bv = *(const short8*)((const char*)xs + tr * 128 +
                                                 ((cg ^ (tr & 7)) << 4));
#pragma unroll
                    for (int i = 0; i < 4; ++i)
                        acc[i][j] = __builtin_amdgcn_mfma_f32_16x16x32_bf16(
                            A[i], Bv, acc[i][j], 0, 0, 0);
                }
            }
            asm volatile("s_waitcnt vmcnt(0)" ::: "memory");
        }
    }

#pragma unroll
    for (int i = 0; i < 4; ++i)
#pragma unroll
        for (int j = 0; j < 6; ++j) {
            const int tt = t0 + j * 16 + l15;
            if (tt < TOUT) {
                float* op = out + ((size_t)b * OEXC + o0 + i * 16 + l4 * 4) * TOUT + tt;
#pragma unroll
                for (int r = 0; r < 4; ++r) op[(size_t)r * TOUT] = acc[i][j][r];
            }
        }
}

__global__ __launch_bounds__(128)
void conv_mfma_inh(const unsigned short* __restrict__ xTh, const unsigned short* __restrict__ xTl,
                   const unsigned short* __restrict__ kbh, const unsigned short* __restrict__ kbl,
                   float* __restrict__ cinh) {
    __shared__ unsigned short xsh[120 * 64];
    __shared__ unsigned short xsl[120 * 64];
    __shared__ unsigned short ksh[2][64 * 64];
    __shared__ unsigned short ksl[2][64 * 64];

    const int tid  = threadIdx.x;
    const int wave = tid >> 6;
    const int lane = tid & 63;
    const int l15 = lane & 15, l4 = lane >> 4, l7 = lane & 7;
    const int b  = blockIdx.z;
    const int t0 = blockIdx.x * 96;
    const int o0 = blockIdx.y * 64;
    const int wtb = wave * 48;

    const int ld_row = lane >> 3;
    const int ld_swz = ((l7 ^ ld_row) << 4);

    f32x4 acc[4][3];
#pragma unroll
    for (int i = 0; i < 4; ++i)
#pragma unroll
        for (int j = 0; j < 3; ++j) acc[i][j] = (f32x4)0.f;

    const char* xrh = (const char*)xTh + ((size_t)b * TROWS + t0) * (IPAD * 2);
    const char* xrl = (const char*)xTl + ((size_t)b * TROWS + t0) * (IPAD * 2);
    const unsigned short* kb = wave ? kbl : kbh;

    for (int ic = 0; ic < 11; ++ic) {
        const int ic0 = ic * 64;
        __syncthreads();
        for (int j = wave; j < 15; j += 2) {
            gload_lds16(xrh + (size_t)(8 * j + ld_row) * (IPAD * 2) + ic0 * 2 + ld_swz,
                        (char*)xsh + j * 1024);
            gload_lds16(xrl + (size_t)(8 * j + ld_row) * (IPAD * 2) + ic0 * 2 + ld_swz,
                        (char*)xsl + j * 1024);
        }
        {
            char* kd = wave ? (char*)ksl[0] : (char*)ksh[0];
#pragma unroll
            for (int j = 0; j < 8; ++j)
                gload_lds16((const char*)kb +
                                ((size_t)(0 * OINH + o0 + 8 * j + ld_row)) * (IPAD * 2) +
                                ic0 * 2 + ld_swz,
                            kd + j * 1024);
        }
        asm volatile("s_waitcnt vmcnt(0)" ::: "memory");
        __syncthreads();

        for (int d = 0; d < DD; ++d) {
            const int cur = d & 1;
            if (d < DD - 1) {
                char* kd = wave ? (char*)ksl[cur ^ 1] : (char*)ksh[cur ^ 1];
#pragma unroll
                for (int j = 0; j < 8; ++j)
                    gload_lds16((const char*)kb +
                                    ((size_t)((d + 1) * OINH + o0 + 8 * j + ld_row)) * (IPAD * 2) +
                                    ic0 * 2 + ld_swz,
                                kd + j * 1024);
            }
            const char* kph = (const char*)ksh[cur];
            const char* kpl = (const char*)ksl[cur];
#pragma unroll
            for (int k2 = 0; k2 < 2; ++k2) {
                const int cg = k2 * 4 + l4;
                short8 Ah[4], Al[4];
#pragma unroll
                for (int i = 0; i < 4; ++i) {
                    Ah[i] = *(const short8*)(kph + (i * 16 + l15) * 128 + ((cg ^ l7) << 4));
                    Al[i] = *(const short8*)(kpl + (i * 16 + l15) * 128 + ((cg ^ l7) << 4));
                }
#pragma unroll
                for (int j = 0; j < 3; ++j) {
                    const int tr = wtb + j * 16 + l15 + d;
                    short8 Bh = *(const short8*)((const char*)xsh + tr * 128 +
                                                 ((cg ^ (tr & 7)) << 4));
                    short8 Bl = *(const short8*)((const char*)xsl + tr * 128 +
                                                 ((cg ^ (tr & 7)) << 4));
#pragma unroll
                    for (int i = 0; i < 4; ++i) {
                        acc[i][j] = __builtin_amdgcn_mfma_f32_16x16x32_bf16(
                            Ah[i], Bh, acc[i][j], 0, 0, 0);
                        acc[i][j] = __builtin_amdgcn_mfma_f32_16x16x32_bf16(
                            Ah[i], Bl, acc[i][j], 0, 0, 0);
                        acc[i][j] = __builtin_amdgcn_mfma_f32_16x16x32_bf16(
                            Al[i], Bh, acc[i][j], 0, 0, 0);
                    }
                }
            }
            asm volatile("s_waitcnt vmcnt(0)" ::: "memory");
            __syncthreads();
        }
    }

#pragma unroll
    for (int i = 0; i < 4; ++i)
#pragma unroll
        for (int j = 0; j < 3; ++j) {
            const int tt = t0 + wtb + j * 16 + l15;
            if (tt < TOUT) {
                float* op = cinh + ((size_t)b * OINH + o0 + i * 16 + l4 * 4) * TOUT + tt;
#pragma unroll
                for (int r = 0; r < 4; ++r) op[(size_t)r * TOUT] = acc[i][j][r];
            }
        }
}

__global__ __launch_bounds__(256)
void conv_dcls_fb(const float* __restrict__ x, const float* __restrict__ kt,
                  float* __restrict__ out, int O) {
    __shared__ float k_lds[100 * 128];
    __shared__ float x_lds[4 * 88];

    const int tid = threadIdx.x;
    const int tx = tid & 7;
    const int ty = tid >> 3;
    const int b  = blockIdx.z;
    const int t0 = blockIdx.x * 64;
    const int o0 = blockIdx.y * 128;
    const int tlim = TIN - t0;

    float acc[4][8];
#pragma unroll
    for (int ro = 0; ro < 4; ++ro)
#pragma unroll
        for (int rt = 0; rt < 8; ++rt) acc[ro][rt] = 0.f;

    for (int chunk = 0; chunk < 175; ++chunk) {
        const int i0 = chunk * 4;
        __syncthreads();
#pragma unroll
        for (int s = 0; s < 13; ++s) {
            int f = tid + s * 256;
            if (f < 3200) {
                int j = f >> 5, o4 = f & 31;
                ((float4*)k_lds)[f] =
                    *(const float4*)(kt + (size_t)(i0 * DD + j) * O + o0 + o4 * 4);
            }
        }
        if (tid < 88) {
            int icc = tid / 22, wq = tid % 22;
            float4 v = make_float4(0.f, 0.f, 0.f, 0.f);
            if (wq * 4 < tlim)
                v = *(const float4*)(x + (size_t)(b * CI + i0 + icc) * TIN + t0 + wq * 4);
            ((float4*)x_lds)[tid] = v;
        }
        __syncthreads();
#pragma unroll
        for (int icc = 0; icc < 4; ++icc) {
            float xv[32];
#pragma unroll
            for (int wq = 0; wq < 8; ++wq)
                *(float4*)(xv + 4 * wq) = ((const float4*)(x_lds + icc * 88))[tx * 2 + wq];
#pragma unroll
            for (int d = 0; d < DD; ++d) {
                float4 kv = ((const float4*)(k_lds + (icc * DD + d) * 128))[ty];
                float kvv[4] = {kv.x, kv.y, kv.z, kv.w};
#pragma unroll
                for (int ro = 0; ro < 4; ++ro)
#pragma unroll
                    for (int rt = 0; rt < 8; ++rt)
                        acc[ro][rt] += kvv[ro] * xv[rt + d];
            }
        }
    }
    const int tvalid = TOUT - t0;
#pragma unroll
    for (int ro = 0; ro < 4; ++ro) {
        float* op = out + (size_t)(b * O + o0 + ty * 4 + ro) * TOUT + t0;
#pragma unroll
        for (int u = 0; u < 2; ++u) {
            int toff = tx * 8 + u * 4;
            if (toff < tvalid) {
                float4 v = make_float4(acc[ro][u * 4 + 0], acc[ro][u * 4 + 1],
                                       acc[ro][u * 4 + 2], acc[ro][u * 4 + 3]);
                *(float4*)(op + toff) = v;
            }
        }
    }
}

__global__ void bn_stats(const float* __restrict__ cinh, const float* __restrict__ gamma,
                         const float* __restrict__ beta, float* __restrict__ scale,
                         float* __restrict__ shift) {
    const int c = blockIdx.x, tid = threadIdx.x;
    float sum = 0.f, sq = 0.f;
    for (int idx = tid; idx < BB * TOUT; idx += 256) {
        int b = idx / TOUT, t = idx - b * TOUT;
        float v = cinh[(size_t)(b * OINH + c) * TOUT + t];
        sum += v; sq += v * v;
    }
#pragma unroll
    for (int off = 32; off; off >>= 1) {
        sum += __shfl_down(sum, off);
        sq  += __shfl_down(sq, off);
    }
    __shared__ float ls[8];
    int wid = tid >> 6;
    if ((tid & 63) == 0) { ls[wid * 2] = sum; ls[wid * 2 + 1] = sq; }
    __syncthreads();
    if (tid == 0) {
        float S = 0.f, Q = 0.f;
#pragma unroll
        for (int wv = 0; wv < 4; ++wv) { S += ls[wv * 2]; Q += ls[wv * 2 + 1]; }
        const float n = (float)(BB * TOUT);
        float mean = S / n;
        float var  = Q / n - mean * mean;
        float rs   = 1.f / sqrtf(var + 1e-5f);
        float sc   = gamma[c] * rs;
        scale[c] = sc;
        shift[c] = beta[c] - mean * sc;
    }
}

__global__ void lif_kernel(const float* __restrict__ cinh, const float* __restrict__ scale,
                           const float* __restrict__ shift, unsigned char* __restrict__ spk) {
    const int b = blockIdx.x, c = threadIdx.x;
    const float sc = scale[c], sh = shift[c];
    const float* row = cinh + (size_t)(b * OINH + c) * TOUT;
    float v = 0.f;
    for (int t = 0; t < TOUT; ++t) {
        float xin = row[t] * sc + sh;
        v = 0.5f * v + xin;
        unsigned char s = (v >= 1.f) ? 1 : 0;
        spk[((size_t)t * BB + b) * OINH + c] = s;
        v = (v >= 1.f) ? 0.f : v;
    }
}

__global__ __launch_bounds__(256)
void finale(const unsigned char* __restrict__ spk, const float* __restrict__ wt,
            float* __restrict__ out) {
    __shared__ float s_lds[64 * 129];
    const int tid = threadIdx.x;
    const int tx = tid & 15, ty = tid >> 4;
    const int b = blockIdx.z, t0 = blockIdx.x * 64, o0 = blockIdx.y * 64;

#pragma unroll
    for (int s = 0; s < 32; ++s) {
        int f = tid + s * 256;
        int tt = f >> 7, c = f & 127;
        float v = 0.f;
        if (t0 + tt < TOUT) v = (float)spk[((size_t)(t0 + tt) * BB + b) * OINH + c];
        s_lds[tt * 129 + c] = v;
    }
    __syncthreads();

    float acc[4][4] = {{0.f}};
#pragma unroll 4
    for (int c = 0; c < 128; ++c) {
        float4 wv = *(const float4*)(wt + c * OEXC + o0 + ty * 4);
        float wvv[4] = {wv.x, wv.y, wv.z, wv.w};
        float sv[4];
#pragma unroll
        for (int rt = 0; rt < 4; ++rt) sv[rt] = s_lds[(tx * 4 + rt) * 129 + c];
#pragma unroll
        for (int ro = 0; ro < 4; ++ro)
#pragma unroll
            for (int rt = 0; rt < 4; ++rt)
                acc[ro][rt] += wvv[ro] * sv[rt];
    }

    const int tvalid = TOUT - t0;
    if (tx * 4 < tvalid) {
#pragma unroll
        for (int ro = 0; ro < 4; ++ro) {
            float* op = out + (size_t)(b * OEXC + o0 + ty * 4 + ro) * TOUT + t0 + tx * 4;
            float4 v = *(float4*)op;
            v.x += acc[ro][0]; v.y += acc[ro][1]; v.z += acc[ro][2]; v.w += acc[ro][3];
            *(float4*)op = v;
        }
    }
}

// ---------------------------------------------------------------------------
extern "C" void kernel_launch(void* const* d_in, const int* in_sizes, int n_in,
                              void* d_out, int out_size, void* d_ws, size_t ws_size,
                              hipStream_t stream) {
    const float* x       = (const float*)d_in[0];
    const float* W_inh   = (const float*)d_in[1];
    const float* P_inh   = (const float*)d_in[2];
    const float* SIG_inh = (const float*)d_in[3];
    const float* W_exc   = (const float*)d_in[4];
    const float* P_exc   = (const float*)d_in[5];
    const float* SIG_exc = (const float*)d_in[6];
    const float* w_ei    = (const float*)d_in[7];
    const float* gamma   = (const float*)d_in[8];
    const float* beta    = (const float*)d_in[9];
    float* out = (float*)d_out;

    const size_t XT_ELEMS   = (size_t)BB * TROWS * IPAD;
    const size_t KEXC_ELEMS = (size_t)DD * OEXC * IPAD;
    const size_t KINH_ELEMS = (size_t)DD * OINH * IPAD;
    const size_t CINH_ELEMS = (size_t)BB * OINH * TOUT;
    const size_t PEXC_ELEMS = (size_t)BB * OEXC * TOUT;

    const size_t NEED_FAST = 2 * XT_ELEMS * 2 + KEXC_ELEMS * 2 + 2 * KINH_ELEMS * 2 +
                             CINH_ELEMS * 4 + OINH * OEXC * 4 + CINH_ELEMS;
    const size_t NEED_FAST2 = (2 * XT_ELEMS + KEXC_ELEMS + 2 * KINH_ELEMS) * 2 +
                              (PEXC_ELEMS + 2 * CINH_ELEMS + OINH * OEXC + 256) * 4 +
                              CINH_ELEMS;

    if (ws_size >= NEED_FAST2) {
        unsigned short* xTh = (unsigned short*)d_ws;
        unsigned short* xTl = xTh + XT_ELEMS;
        unsigned short* kb2 = xTl + XT_ELEMS;
        unsigned short* kbh = kb2 + KEXC_ELEMS;
        unsigned short* kbl = kbh + KINH_ELEMS;
        float* pexc1 = (float*)(kbl + KINH_ELEMS);
        float* cinh  = pexc1 + PEXC_ELEMS;
        float* pinh1 = cinh + CINH_ELEMS;
        float* wt    = pinh1 + CINH_ELEMS;
        float* scale = wt + OINH * OEXC;
        float* shift = scale + OINH;
        unsigned char* spk = (unsigned char*)(shift + OINH);

        hipLaunchKernelGGL(kexc_build, dim3((OEXC * IPAD + 255) / 256), dim3(256), 0, stream,
                           W_exc, P_exc, SIG_exc, kb2);
        hipLaunchKernelGGL(kinh_build, dim3((OINH * IPAD + 255) / 256), dim3(256), 0, stream,
                           W_inh, P_inh, SIG_inh, kbh, kbl);
        hipLaunchKernelGGL(xt_kernel, dim3(5, 11, 64), dim3(256), 0, stream, x, xTh, xTl);
        hipLaunchKernelGGL(wt_kernel, dim3(128), dim3(256), 0, stream, w_ei, wt);

        hipLaunchKernelGGL(conv_fused_v8, dim3(6, 4, 32), dim3(256), 0, stream,
                           xTh, xTl, kb2, kbh, kbl, out, pexc1, cinh, pinh1);

        hipLaunchKernelGGL(add_exc, dim3((unsigned)(PEXC_ELEMS / 4 / 256)), dim3(256), 0, stream,
                           pexc1, out);
        hipLaunchKernelGGL(bn_stats2, dim3(128), dim3(256), 0, stream,
                           cinh, pinh1, gamma, beta, scale, shift);
        hipLaunchKernelGGL(lif2, dim3(64), dim3(128), 0, stream, cinh, scale, shift, spk);
        hipLaunchKernelGGL(finale, dim3(5, 4, 64), dim3(256), 0, stream, spk, wt, out);
    } else if (ws_size >= NEED_FAST) {
        unsigned short* xTh = (unsigned short*)d_ws;
        unsigned short* xTl = xTh + XT_ELEMS;
        unsigned short* kb2 = xTl + XT_ELEMS;
        unsigned short* kbh = kb2 + KEXC_ELEMS;
        unsigned short* kbl = kbh + KINH_ELEMS;
        float* cinh  = (float*)(kbl + KINH_ELEMS);
        float* wt    = cinh + CINH_ELEMS;
        float* scale = wt + OINH * OEXC;
        float* shift = scale + OINH;
        unsigned char* spk = (unsigned char*)(shift + OINH);

        hipLaunchKernelGGL(kexc_build, dim3((OEXC * IPAD + 255) / 256), dim3(256), 0, stream,
                           W_exc, P_exc, SIG_exc, kb2);
        hipLaunchKernelGGL(kinh_build, dim3((OINH * IPAD + 255) / 256), dim3(256), 0, stream,
                           W_inh, P_inh, SIG_inh, kbh, kbl);
        hipLaunchKernelGGL(xt_kernel, dim3(5, 11, 64), dim3(256), 0, stream, x, xTh, xTl);
        hipLaunchKernelGGL(wt_kernel, dim3(128), dim3(256), 0, stream, w_ei, wt);

        hipLaunchKernelGGL(conv_mfma, dim3(3, 2, 64), dim3(128), 0, stream, xTh, kb2, out);
        hipLaunchKernelGGL(conv_mfma_inh, dim3(3, 2, 64), dim3(128), 0, stream,
                           xTh, xTl, kbh, kbl, cinh);

        hipLaunchKernelGGL(bn_stats, dim3(128), dim3(256), 0, stream, cinh, gamma, beta, scale, shift);
        hipLaunchKernelGGL(lif_kernel, dim3(64), dim3(128), 0, stream, cinh, scale, shift, spk);
        hipLaunchKernelGGL(finale, dim3(5, 4, 64), dim3(256), 0, stream, spk, wt, out);
    } else {
        unsigned short* xTh = (unsigned short*)d_ws;
        unsigned short* kb2 = xTh + XT_ELEMS;
        float* kt_inh = (float*)(kb2 + KEXC_ELEMS);
        float* cinh   = kt_inh + 2240000;
        float* wt     = cinh + CINH_ELEMS;
        float* scale  = wt + OINH * OEXC;
        float* shift  = scale + OINH;
        unsigned char* spk = (unsigned char*)(shift + OINH);

        hipLaunchKernelGGL(kexc_build, dim3((OEXC * IPAD + 255) / 256), dim3(256), 0, stream,
                           W_exc, P_exc, SIG_exc, kb2);
        hipLaunchKernelGGL(build_kt, dim3(350), dim3(256), 0, stream,
                           W_inh, P_inh, SIG_inh, kt_inh, OINH);
        hipLaunchKernelGGL(xt_kernel, dim3(5, 11, 64), dim3(256), 0, stream, x, xTh,
                           (unsigned short*)nullptr);
        hipLaunchKernelGGL(wt_kernel, dim3(128), dim3(256), 0, stream, w_ei, wt);

        hipLaunchKernelGGL(conv_mfma, dim3(3, 2, 64), dim3(128), 0, stream, xTh, kb2, out);
        hipLaunchKernelGGL(conv_dcls_fb, dim3(5, 1, 64), dim3(256), 0, stream, x, kt_inh, cinh, OINH);

        hipLaunchKernelGGL(bn_stats, dim3(128), dim3(256), 0, stream, cinh, gamma, beta, scale, shift);
        hipLaunchKernelGGL(lif_kernel, dim3(64), dim3(128), 0, stream, cinh, scale, shift, spk);
        hipLaunchKernelGGL(finale, dim3(5, 4, 64), dim3(256), 0, stream, spk, wt, out);
    }
}

// Round 15
// 478.854 us; speedup vs baseline: 1.0342x; 1.0342x over previous
//
#include <hip/hip_runtime.h>
#include <math.h>

#define CI   700
#define TIN  300
#define DD   25
#define TOUT 276
#define BB   64
#define OINH 128
#define OEXC 256

#define TROWS 312
#define IPAD  704

typedef __attribute__((ext_vector_type(8))) short short8;
typedef __attribute__((ext_vector_type(4))) float f32x4;
typedef __attribute__((ext_vector_type(8))) unsigned short ushort8v;

static __device__ __forceinline__ unsigned short f2bf(float f) {
    unsigned int u = __float_as_uint(f);
    unsigned int r = (u + 0x7FFFu + ((u >> 16) & 1u)) >> 16;
    return (unsigned short)r;
}
static __device__ __forceinline__ float bf2f(unsigned short h) {
    return __uint_as_float(((unsigned int)h) << 16);
}
static __device__ __forceinline__ void gload_lds16(const void* g, void* l) {
    __builtin_amdgcn_global_load_lds(
        (const __attribute__((address_space(1))) unsigned int*)g,
        (__attribute__((address_space(3))) unsigned int*)l, 16, 0, 0);
}

// ---------------------------------------------------------------------------
__global__ void build_kt(const float* __restrict__ W, const float* __restrict__ P,
                         const float* __restrict__ SIG, float* __restrict__ kt, int O) {
    int n = blockIdx.x * 256 + threadIdx.x;
    if (n >= O * CI) return;
    int o = n % O, i = n / O;
    float w   = fabsf(W[o * CI + i]);
    float p   = fminf(fmaxf(P[o * CI + i], -12.f), 12.f) + 12.f;
    float sig = fabsf(SIG[o * CI + i]) + 0.27f;
    float inv = 1.f / sig;
    float g[DD]; float sum = 0.f;
#pragma unroll
    for (int d = 0; d < DD; ++d) {
        float e = ((float)d - p) * inv;
        g[d] = expf(-0.5f * e * e); sum += g[d];
    }
    float sc = w / (sum + 1e-7f);
#pragma unroll
    for (int d = 0; d < DD; ++d)
        kt[(i * DD + d) * O + o] = g[d] * sc;
}

// ---------------------------------------------------------------------------
__global__ void kexc_build(const float* __restrict__ W, const float* __restrict__ P,
                           const float* __restrict__ SIG, unsigned short* __restrict__ kb2) {
    int n = blockIdx.x * 256 + threadIdx.x;
    if (n >= OEXC * IPAD) return;
    int o = n / IPAD, ip = n % IPAD;
    if (ip >= CI) {
#pragma unroll
        for (int d = 0; d < DD; ++d)
            kb2[((size_t)d * OEXC + o) * IPAD + ip] = 0;
        return;
    }
    float w   = fabsf(W[o * CI + ip]);
    float p   = fminf(fmaxf(P[o * CI + ip], -12.f), 12.f) + 12.f;
    float sig = fabsf(SIG[o * CI + ip]) + 0.27f;
    float inv = 1.f / sig;
    float g[DD]; float sum = 0.f;
#pragma unroll
    for (int d = 0; d < DD; ++d) {
        float e = ((float)d - p) * inv;
        g[d] = expf(-0.5f * e * e); sum += g[d];
    }
    float sc = w / (sum + 1e-7f);
#pragma unroll
    for (int d = 0; d < DD; ++d)
        kb2[((size_t)d * OEXC + o) * IPAD + ip] = f2bf(g[d] * sc);
}

// ---------------------------------------------------------------------------
__global__ void kinh_build(const float* __restrict__ W, const float* __restrict__ P,
                           const float* __restrict__ SIG,
                           unsigned short* __restrict__ kbh, unsigned short* __restrict__ kbl) {
    int n = blockIdx.x * 256 + threadIdx.x;
    if (n >= OINH * IPAD) return;
    int o = n / IPAD, ip = n % IPAD;
    if (ip >= CI) {
#pragma unroll
        for (int d = 0; d < DD; ++d) {
            kbh[((size_t)d * OINH + o) * IPAD + ip] = 0;
            kbl[((size_t)d * OINH + o) * IPAD + ip] = 0;
        }
        return;
    }
    float w   = fabsf(W[o * CI + ip]);
    float p   = fminf(fmaxf(P[o * CI + ip], -12.f), 12.f) + 12.f;
    float sig = fabsf(SIG[o * CI + ip]) + 0.27f;
    float inv = 1.f / sig;
    float g[DD]; float sum = 0.f;
#pragma unroll
    for (int d = 0; d < DD; ++d) {
        float e = ((float)d - p) * inv;
        g[d] = expf(-0.5f * e * e); sum += g[d];
    }
    float sc = w / (sum + 1e-7f);
#pragma unroll
    for (int d = 0; d < DD; ++d) {
        float v = g[d] * sc;
        unsigned short h = f2bf(v);
        kbh[((size_t)d * OINH + o) * IPAD + ip] = h;
        kbl[((size_t)d * OINH + o) * IPAD + ip] = f2bf(v - bf2f(h));
    }
}

// ---------------------------------------------------------------------------
__global__ __launch_bounds__(256)
void xt_kernel(const float* __restrict__ x, unsigned short* __restrict__ xTh,
               unsigned short* __restrict__ xTl) {
    __shared__ float tile[64][65];
    const int tid = threadIdx.x;
    const int t0 = blockIdx.x * 64, i0 = blockIdx.y * 64, b = blockIdx.z;
#pragma unroll
    for (int s = 0; s < 16; ++s) {
        int f = s * 256 + tid;
        int tt = f & 63, ii = f >> 6;
        float v = 0.f;
        if (t0 + tt < TIN && i0 + ii < CI)
            v = x[((size_t)b * CI + i0 + ii) * TIN + t0 + tt];
        tile[tt][ii] = v;
    }
    __syncthreads();
#pragma unroll
    for (int s = 0; s < 2; ++s) {
        int f = s * 256 + tid;
        int tt = f >> 3, g = f & 7;
        if (t0 + tt < TROWS) {
            ushort8v vh, vl;
#pragma unroll
            for (int e = 0; e < 8; ++e) {
                float v = tile[tt][g * 8 + e];
                unsigned short h = f2bf(v);
                vh[e] = h;
                vl[e] = f2bf(v - bf2f(h));
            }
            size_t off = ((size_t)b * TROWS + t0 + tt) * IPAD + i0 + g * 8;
            *(ushort8v*)(xTh + off) = vh;
            if (xTl) *(ushort8v*)(xTl + off) = vl;
        }
    }
}

// ---------------------------------------------------------------------------
__global__ void wt_kernel(const float* __restrict__ w, float* __restrict__ wt) {
    int n = blockIdx.x * 256 + threadIdx.x;
    if (n >= OINH * OEXC) return;
    int o = n % OEXC, c = n / OEXC;
    wt[c * OEXC + o] = -fabsf(w[o * OINH + c]);
}

// ===========================================================================
// FUSED conv v7 (round-11 best: conv 363 us, MfmaUtil 53.6%, total 479 us).
// Batch-pairing: 2 b per block, waves = (wb = wave>>1 batch, wo = wave&1).
// grid (6, 4, 32), 256 thr:
//   blockIdx.x: tt = x%3 (t0 = tt*96), ksp = x/3 (chunks [11ksp, 11ksp+11))
//   blockIdx.y: 0,1 = exc (o0 = y*128); 2,3 = inh (o0 = (y-2)*64)
//   blockIdx.z: batch pair bp -> b = 2*bp + wb
// Per wave: exc 64o x 96t (acc[4][6]); inh 32o x 96t (acc[2][6], 3-term).
// k dbuf per-d with vmcnt(0)+lockstep barrier (proven race-free v6 pattern);
// wb-partners duplicate-write identical k bytes.
// LDS 48 KB: exc x[2][8KB]@0 + k@16384 (buf*2+wo)*4096;
//            inh xh[2]@0, xl[2]@16384, k@32768 (buf*2+wo)*4096 (kh2K|kl2K).
// Swizzle identical to round 6 (proven 0-conflict).
// ===========================================================================
__global__ __launch_bounds__(256, 3)
void conv_fused_v7(const unsigned short* __restrict__ xTh, const unsigned short* __restrict__ xTl,
                   const unsigned short* __restrict__ kb2,
                   const unsigned short* __restrict__ kbh, const unsigned short* __restrict__ kbl,
                   float* __restrict__ pexc0, float* __restrict__ pexc1,
                   float* __restrict__ pinh0, float* __restrict__ pinh1) {
    __shared__ unsigned short lds[24576];          // 48 KB union

    const int tid  = threadIdx.x;
    const int wave = tid >> 6;
    const int lane = tid & 63;
    const int wb   = wave >> 1;                    // batch within pair
    const int wo   = wave & 1;                     // o-half
    const int l15 = lane & 15, l4 = lane >> 4;
    const int tt   = blockIdx.x % 3;
    const int ksp  = blockIdx.x / 3;
    const int role = blockIdx.y;
    const int bp   = blockIdx.z;
    const int t0   = tt * 96;
    const int icb  = ksp * 11;

    const int ld_r = lane >> 2;
    const int ld_c = (((lane & 3) ^ ((lane >> 3) & 3)) << 4);
    const int SA   = (l15 >> 1) & 3;

    const size_t xstride = (size_t)IPAD * 2;

    if (role < 2) {
        // ============================ EXC ============================
        const int o0  = role * 128;
        const int o0w = o0 + wo * 64;
        const int b   = 2 * bp + wb;

        f32x4 acc[4][6];
#pragma unroll
        for (int i = 0; i < 4; ++i)
#pragma unroll
            for (int j = 0; j < 6; ++j) acc[i][j] = (f32x4)0.f;

        for (int c = 0; c < 11; ++c) {
            const size_t cb = (size_t)(icb + c) * 64;
            __syncthreads();
            // stage x windows for both batches: 16 issues over 4 waves
            for (int j = wave; j < 16; j += 4) {
                const int q = j >> 3, jj = j & 7;
                const char* xb = (const char*)xTh +
                    ((size_t)(2 * bp + q) * TROWS + t0) * xstride;
                gload_lds16(xb + (size_t)(16 * jj + ld_r) * xstride + cb + ld_c,
                            (char*)lds + q * 8192 + jj * 1024);
            }
            // stage k d=0 into buf0 (own o-half; wb-partner writes same bytes)
            {
                const char* kbase = (const char*)kb2 + (size_t)o0w * xstride + cb;
                char* kdst = (char*)lds + 16384 + (0 * 2 + wo) * 4096;
#pragma unroll
                for (int j = 0; j < 4; ++j)
                    gload_lds16(kbase + (size_t)(16 * j + ld_r) * xstride + ld_c,
                                kdst + j * 1024);
            }
            asm volatile("s_waitcnt vmcnt(0)" ::: "memory");
            __syncthreads();

            for (int d = 0; d < DD; ++d) {
                const int cur = d & 1;
                if (d < DD - 1) {
                    const char* kbase = (const char*)kb2 +
                        ((size_t)((d + 1) * OEXC) + o0w) * xstride + cb;
                    char* kdst = (char*)lds + 16384 + ((cur ^ 1) * 2 + wo) * 4096;
#pragma unroll
                    for (int j = 0; j < 4; ++j)
                        gload_lds16(kbase + (size_t)(16 * j + ld_r) * xstride + ld_c,
                                    kdst + j * 1024);
                }
                const char* kp = (const char*)lds + 16384 + (cur * 2 + wo) * 4096;
                short8 A[4];
#pragma unroll
                for (int i = 0; i < 4; ++i)
                    A[i] = *(const short8*)(kp + (i * 16 + l15) * 64 + ((l4 ^ SA) << 4));
#pragma unroll
                for (int j = 0; j < 6; ++j) {
                    const int tr = j * 16 + l15 + d;
                    short8 Bv = *(const short8*)((const char*)lds + wb * 8192 + tr * 64 +
                                                 ((l4 ^ ((tr >> 1) & 3)) << 4));
#pragma unroll
                    for (int i = 0; i < 4; ++i)
                        acc[i][j] = __builtin_amdgcn_mfma_f32_16x16x32_bf16(
                            A[i], Bv, acc[i][j], 0, 0, 0);
                }
                asm volatile("s_waitcnt vmcnt(0)" ::: "memory");
                __syncthreads();                   // lockstep: no partner drift
            }
        }
        float* dst = ksp ? pexc1 : pexc0;
#pragma unroll
        for (int i = 0; i < 4; ++i)
#pragma unroll
            for (int j = 0; j < 6; ++j) {
                const int t = t0 + j * 16 + l15;
                if (t < TOUT) {
                    float* op = dst + ((size_t)b * OEXC + o0w + i * 16 + l4 * 4) * TOUT + t;
#pragma unroll
                    for (int r = 0; r < 4; ++r) op[(size_t)r * TOUT] = acc[i][j][r];
                }
            }
    } else {
        // ============================ INH ============================
        const int o0  = (role - 2) * 64;
        const int o0w = o0 + wo * 32;
        const int b   = 2 * bp + wb;

        f32x4 acc[2][6];
#pragma unroll
        for (int i = 0; i < 2; ++i)
#pragma unroll
            for (int j = 0; j < 6; ++j) acc[i][j] = (f32x4)0.f;

        for (int c = 0; c < 11; ++c) {
            const size_t cb = (size_t)(icb + c) * 64;
            __syncthreads();
            // x hi+lo for both batches: 32 issues over 4 waves (8 each)
            for (int j = wave; j < 16; j += 4) {
                const int q = j >> 3, jj = j & 7;
                const size_t rowoff = ((size_t)(2 * bp + q) * TROWS + t0) * xstride +
                                      (size_t)(16 * jj + ld_r) * xstride + cb + ld_c;
                gload_lds16((const char*)xTh + rowoff,
                            (char*)lds + q * 8192 + jj * 1024);
                gload_lds16((const char*)xTl + rowoff,
                            (char*)lds + 16384 + q * 8192 + jj * 1024);
            }
            // k d=0: own 32-o half, kh+kl (wb-partner duplicates)
            {
                const size_t ko = (size_t)o0w * xstride + cb;
                char* kdst = (char*)lds + 32768 + (0 * 2 + wo) * 4096;
#pragma unroll
                for (int j = 0; j < 2; ++j) {
                    gload_lds16((const char*)kbh + ko + (size_t)(16 * j + ld_r) * xstride + ld_c,
                                kdst + j * 1024);
                    gload_lds16((const char*)kbl + ko + (size_t)(16 * j + ld_r) * xstride + ld_c,
                                kdst + 2048 + j * 1024);
                }
            }
            asm volatile("s_waitcnt vmcnt(0)" ::: "memory");
            __syncthreads();

            for (int d = 0; d < DD; ++d) {
                const int cur = d & 1;
                if (d < DD - 1) {
                    const size_t ko = ((size_t)((d + 1) * OINH) + o0w) * xstride + cb;
                    char* kdst = (char*)lds + 32768 + ((cur ^ 1) * 2 + wo) * 4096;
#pragma unroll
                    for (int j = 0; j < 2; ++j) {
                        gload_lds16((const char*)kbh + ko + (size_t)(16 * j + ld_r) * xstride + ld_c,
                                    kdst + j * 1024);
                        gload_lds16((const char*)kbl + ko + (size_t)(16 * j + ld_r) * xstride + ld_c,
                                    kdst + 2048 + j * 1024);
                    }
                }
                const char* kp = (const char*)lds + 32768 + (cur * 2 + wo) * 4096;
                short8 Ah[2], Al[2];
#pragma unroll
                for (int i = 0; i < 2; ++i) {
                    Ah[i] = *(const short8*)(kp + (i * 16 + l15) * 64 + ((l4 ^ SA) << 4));
                    Al[i] = *(const short8*)(kp + 2048 + (i * 16 + l15) * 64 + ((l4 ^ SA) << 4));
                }
#pragma unroll
                for (int j = 0; j < 6; ++j) {
                    const int tr = j * 16 + l15 + d;
                    const int xo = tr * 64 + ((l4 ^ ((tr >> 1) & 3)) << 4);
                    short8 Bh = *(const short8*)((const char*)lds + wb * 8192 + xo);
                    short8 Bl = *(const short8*)((const char*)lds + 16384 + wb * 8192 + xo);
#pragma unroll
                    for (int i = 0; i < 2; ++i) {
                        acc[i][j] = __builtin_amdgcn_mfma_f32_16x16x32_bf16(
                            Ah[i], Bh, acc[i][j], 0, 0, 0);
                        acc[i][j] = __builtin_amdgcn_mfma_f32_16x16x32_bf16(
                            Ah[i], Bl, acc[i][j], 0, 0, 0);
                        acc[i][j] = __builtin_amdgcn_mfma_f32_16x16x32_bf16(
                            Al[i], Bh, acc[i][j], 0, 0, 0);
                    }
                }
                asm volatile("s_waitcnt vmcnt(0)" ::: "memory");
                __syncthreads();                   // lockstep: no partner drift
            }
        }
        float* dst = ksp ? pinh1 : pinh0;
#pragma unroll
        for (int i = 0; i < 2; ++i)
#pragma unroll
            for (int j = 0; j < 6; ++j) {
                const int t = t0 + j * 16 + l15;
                if (t < TOUT) {
                    float* op = dst + ((size_t)b * OINH + o0w + i * 16 + l4 * 4) * TOUT + t;
#pragma unroll
                    for (int r = 0; r < 4; ++r) op[(size_t)r * TOUT] = acc[i][j][r];
                }
            }
    }
}

// ---------------------------------------------------------------------------
__global__ void add_exc(const float* __restrict__ p1, float* __restrict__ out) {
    int n = blockIdx.x * 256 + threadIdx.x;
    float4 a = ((const float4*)out)[n];
    float4 v = ((const float4*)p1)[n];
    a.x += v.x; a.y += v.y; a.z += v.z; a.w += v.w;
    ((float4*)out)[n] = a;
}

// ---------------------------------------------------------------------------
__global__ void bn_stats2(float* __restrict__ cinh, const float* __restrict__ q1,
                          const float* __restrict__ gamma, const float* __restrict__ beta,
                          float* __restrict__ scale, float* __restrict__ shift) {
    const int c = blockIdx.x, tid = threadIdx.x;
    float sum = 0.f, sq = 0.f;
    for (int idx = tid; idx < BB * TOUT; idx += 256) {
        int b = idx / TOUT, t = idx - b * TOUT;
        size_t off = (size_t)(b * OINH + c) * TOUT + t;
        float v = cinh[off] + q1[off];
        cinh[off] = v;
        sum += v; sq += v * v;
    }
#pragma unroll
    for (int off = 32; off; off >>= 1) {
        sum += __shfl_down(sum, off);
        sq  += __shfl_down(sq, off);
    }
    __shared__ float ls[8];
    int wid = tid >> 6;
    if ((tid & 63) == 0) { ls[wid * 2] = sum; ls[wid * 2 + 1] = sq; }
    __syncthreads();
    if (tid == 0) {
        float S = 0.f, Q = 0.f;
#pragma unroll
        for (int wv = 0; wv < 4; ++wv) { S += ls[wv * 2]; Q += ls[wv * 2 + 1]; }
        const float n = (float)(BB * TOUT);
        float mean = S / n;
        float var  = Q / n - mean * mean;
        float rs   = 1.f / sqrtf(var + 1e-5f);
        float sc   = gamma[c] * rs;
        scale[c] = sc;
        shift[c] = beta[c] - mean * sc;
    }
}

// ---------------------------------------------------------------------------
__global__ __launch_bounds__(128)
void lif2(const float* __restrict__ cinh, const float* __restrict__ scale,
          const float* __restrict__ shift, unsigned char* __restrict__ spk) {
    __shared__ float tile[128 * 65];
    const int b = blockIdx.x, c = threadIdx.x;
    const float sc = scale[c], sh = shift[c];
    const float* base = cinh + (size_t)b * OINH * TOUT;
    float v = 0.f;
    for (int tc = 0; tc < TOUT; tc += 64) {
        const int len = (TOUT - tc < 64) ? (TOUT - tc) : 64;
        const int L4 = len >> 2;
        __syncthreads();
        for (int q = c; q < 128 * L4; q += 128) {
            int cc = q / L4, e = q - cc * L4;
            float4 vv = *(const float4*)(base + (size_t)cc * TOUT + tc + e * 4);
            float* dstp = &tile[cc * 65 + e * 4];
            dstp[0] = vv.x; dstp[1] = vv.y; dstp[2] = vv.z; dstp[3] = vv.w;
        }
        __syncthreads();
        for (int t2 = 0; t2 < len; ++t2) {
            float xin = tile[c * 65 + t2] * sc + sh;
            v = 0.5f * v + xin;
            bool s = (v >= 1.f);
            spk[((size_t)(tc + t2) * BB + b) * OINH + c] = s ? 1 : 0;
            v = s ? 0.f : v;
        }
    }
}

// ---------------------------------------------------------------------------
// Fallback kernels (round-4 proven versions).
// ---------------------------------------------------------------------------
__global__ __launch_bounds__(128)
void conv_mfma(const unsigned short* __restrict__ xTh, const unsigned short* __restrict__ kb2,
               float* __restrict__ out) {
    __shared__ unsigned short xs[120 * 64];
    __shared__ unsigned short ks[2][2][64 * 64];

    const int tid  = threadIdx.x;
    const int wave = tid >> 6;
    const int lane = tid & 63;
    const int l15 = lane & 15, l4 = lane >> 4, l7 = lane & 7;
    const int b  = blockIdx.z;
    const int t0 = blockIdx.x * 96;
    const int o0 = blockIdx.y * 128 + wave * 64;

    const int ld_row = lane >> 3;
    const int ld_swz = ((l7 ^ ld_row) << 4);

    f32x4 acc[4][6];
#pragma unroll
    for (int i = 0; i < 4; ++i)
#pragma unroll
        for (int j = 0; j < 6; ++j) acc[i][j] = (f32x4)0.f;

    const char* xrow0 = (const char*)xTh + ((size_t)b * TROWS + t0) * (IPAD * 2);

    for (int ic = 0; ic < 11; ++ic) {
        const int ic0 = ic * 64;
        __syncthreads();
        for (int j = wave; j < 15; j += 2)
            gload_lds16(xrow0 + (size_t)(8 * j + ld_row) * (IPAD * 2) + ic0 * 2 + ld_swz,
                        (char*)xs + j * 1024);
        {
            const char* ksrc = (const char*)kb2 + ((size_t)o0) * (IPAD * 2) + ic0 * 2;
            char* kdst = (char*)ks + (0 * 2 + wave) * 8192;
#pragma unroll
            for (int j = 0; j < 8; ++j)
                gload_lds16(ksrc + (size_t)(8 * j + ld_row) * (IPAD * 2) + ld_swz,
                            kdst + j * 1024);
        }
        asm volatile("s_waitcnt vmcnt(0)" ::: "memory");
        __syncthreads();

        for (int d = 0; d < DD; ++d) {
            const int cur = d & 1;
            if (d < DD - 1) {
                const char* ksrc = (const char*)kb2 +
                    ((size_t)(d + 1) * OEXC + o0) * (IPAD * 2) + ic0 * 2;
                char* kdst = (char*)ks + ((cur ^ 1) * 2 + wave) * 8192;
#pragma unroll
                for (int j = 0; j < 8; ++j)
                    gload_lds16(ksrc + (size_t)(8 * j + ld_row) * (IPAD * 2) + ld_swz,
                                kdst + j * 1024);
            }
            const char* kp = (const char*)ks + (cur * 2 + wave) * 8192;
#pragma unroll
            for (int ks2 = 0; ks2 < 2; ++ks2) {
                const int cg = ks2 * 4 + l4;
                short8 A[4];
#pragma unroll
                for (int i = 0; i < 4; ++i)
                    A[i] = *(const short8*)(kp + (i * 16 + l15) * 128 + ((cg ^ l7) << 4));
#pragma unroll
                for (int j = 0; j < 6; ++j) {
                    const int tr = j * 16 + l15 + d;
                    short8 Bv = *(const short8*)((const char*)xs + tr * 128 +
                                                 ((cg ^ (tr & 7)) << 4));
#pragma unroll
                    for (int i = 0; i < 4; ++i)
                        acc[i][j] = __builtin_amdgcn_mfma_f32_16x16x32_bf16(
                            A[i], Bv, acc[i][j], 0, 0, 0);
                }
            }
            asm volatile("s_waitcnt vmcnt(0)" ::: "memory");
        }
    }

#pragma unroll
    for (int i = 0; i < 4; ++i)
#pragma unroll
        for (int j = 0; j < 6; ++j) {
            const int tt = t0 + j * 16 + l15;
            if (tt < TOUT) {
                float* op = out + ((size_t)b * OEXC + o0 + i * 16 + l4 * 4) * TOUT + tt;
#pragma unroll
                for (int r = 0; r < 4; ++r) op[(size_t)r * TOUT] = acc[i][j][r];
            }
        }
}

__global__ __launch_bounds__(128)
void conv_mfma_inh(const unsigned short* __restrict__ xTh, const unsigned short* __restrict__ xTl,
                   const unsigned short* __restrict__ kbh, const unsigned short* __restrict__ kbl,
                   float* __restrict__ cinh) {
    __shared__ unsigned short xsh[120 * 64];
    __shared__ unsigned short xsl[120 * 64];
    __shared__ unsigned short ksh[2][64 * 64];
    __shared__ unsigned short ksl[2][64 * 64];

    const int tid  = threadIdx.x;
    const int wave = tid >> 6;
    const int lane = tid & 63;
    const int l15 = lane & 15, l4 = lane >> 4, l7 = lane & 7;
    const int b  = blockIdx.z;
    const int t0 = blockIdx.x * 96;
    const int o0 = blockIdx.y * 64;
    const int wtb = wave * 48;

    const int ld_row = lane >> 3;
    const int ld_swz = ((l7 ^ ld_row) << 4);

    f32x4 acc[4][3];
#pragma unroll
    for (int i = 0; i < 4; ++i)
#pragma unroll
        for (int j = 0; j < 3; ++j) acc[i][j] = (f32x4)0.f;

    const char* xrh = (const char*)xTh + ((size_t)b * TROWS + t0) * (IPAD * 2);
    const char* xrl = (const char*)xTl + ((size_t)b * TROWS + t0) * (IPAD * 2);
    const unsigned short* kb = wave ? kbl : kbh;

    for (int ic = 0; ic < 11; ++ic) {
        const int ic0 = ic * 64;
        __syncthreads();
        for (int j = wave; j < 15; j += 2) {
            gload_lds16(xrh + (size_t)(8 * j + ld_row) * (IPAD * 2) + ic0 * 2 + ld_swz,
                        (char*)xsh + j * 1024);
            gload_lds16(xrl + (size_t)(8 * j + ld_row) * (IPAD * 2) + ic0 * 2 + ld_swz,
                        (char*)xsl + j * 1024);
        }
        {
            char* kd = wave ? (char*)ksl[0] : (char*)ksh[0];
#pragma unroll
            for (int j = 0; j < 8; ++j)
                gload_lds16((const char*)kb +
                                ((size_t)(0 * OINH + o0 + 8 * j + ld_row)) * (IPAD * 2) +
                                ic0 * 2 + ld_swz,
                            kd + j * 1024);
        }
        asm volatile("s_waitcnt vmcnt(0)" ::: "memory");
        __syncthreads();

        for (int d = 0; d < DD; ++d) {
            const int cur = d & 1;
            if (d < DD - 1) {
                char* kd = wave ? (char*)ksl[cur ^ 1] : (char*)ksh[cur ^ 1];
#pragma unroll
                for (int j = 0; j < 8; ++j)
                    gload_lds16((const char*)kb +
                                    ((size_t)((d + 1) * OINH + o0 + 8 * j + ld_row)) * (IPAD * 2) +
                                    ic0 * 2 + ld_swz,
                                kd + j * 1024);
            }
            const char* kph = (const char*)ksh[cur];
            const char* kpl = (const char*)ksl[cur];
#pragma unroll
            for (int k2 = 0; k2 < 2; ++k2) {
                const int cg = k2 * 4 + l4;
                short8 Ah[4], Al[4];
#pragma unroll
                for (int i = 0; i < 4; ++i) {
                    Ah[i] = *(const short8*)(kph + (i * 16 + l15) * 128 + ((cg ^ l7) << 4));
                    Al[i] = *(const short8*)(kpl + (i * 16 + l15) * 128 + ((cg ^ l7) << 4));
                }
#pragma unroll
                for (int j = 0; j < 3; ++j) {
                    const int tr = wtb + j * 16 + l15 + d;
                    short8 Bh = *(const short8*)((const char*)xsh + tr * 128 +
                                                 ((cg ^ (tr & 7)) << 4));
                    short8 Bl = *(const short8*)((const char*)xsl + tr * 128 +
                                                 ((cg ^ (tr & 7)) << 4));
#pragma unroll
                    for (int i = 0; i < 4; ++i) {
                        acc[i][j] = __builtin_amdgcn_mfma_f32_16x16x32_bf16(
                            Ah[i], Bh, acc[i][j], 0, 0, 0);
                        acc[i][j] = __builtin_amdgcn_mfma_f32_16x16x32_bf16(
                            Ah[i], Bl, acc[i][j], 0, 0, 0);
                        acc[i][j] = __builtin_amdgcn_mfma_f32_16x16x32_bf16(
                            Al[i], Bh, acc[i][j], 0, 0, 0);
                    }
                }
            }
            asm volatile("s_waitcnt vmcnt(0)" ::: "memory");
            __syncthreads();
        }
    }

#pragma unroll
    for (int i = 0; i < 4; ++i)
#pragma unroll
        for (int j = 0; j < 3; ++j) {
            const int tt = t0 + wtb + j * 16 + l15;
            if (tt < TOUT) {
                float* op = cinh + ((size_t)b * OINH + o0 + i * 16 + l4 * 4) * TOUT + tt;
#pragma unroll
                for (int r = 0; r < 4; ++r) op[(size_t)r * TOUT] = acc[i][j][r];
            }
        }
}

__global__ __launch_bounds__(256)
void conv_dcls_fb(const float* __restrict__ x, const float* __restrict__ kt,
                  float* __restrict__ out, int O) {
    __shared__ float k_lds[100 * 128];
    __shared__ float x_lds[4 * 88];

    const int tid = threadIdx.x;
    const int tx = tid & 7;
    const int ty = tid >> 3;
    const int b  = blockIdx.z;
    const int t0 = blockIdx.x * 64;
    const int o0 = blockIdx.y * 128;
    const int tlim = TIN - t0;

    float acc[4][8];
#pragma unroll
    for (int ro = 0; ro < 4; ++ro)
#pragma unroll
        for (int rt = 0; rt < 8; ++rt) acc[ro][rt] = 0.f;

    for (int chunk = 0; chunk < 175; ++chunk) {
        const int i0 = chunk * 4;
        __syncthreads();
#pragma unroll
        for (int s = 0; s < 13; ++s) {
            int f = tid + s * 256;
            if (f < 3200) {
                int j = f >> 5, o4 = f & 31;
                ((float4*)k_lds)[f] =
                    *(const float4*)(kt + (size_t)(i0 * DD + j) * O + o0 + o4 * 4);
            }
        }
        if (tid < 88) {
            int icc = tid / 22, wq = tid % 22;
            float4 v = make_float4(0.f, 0.f, 0.f, 0.f);
            if (wq * 4 < tlim)
                v = *(const float4*)(x + (size_t)(b * CI + i0 + icc) * TIN + t0 + wq * 4);
            ((float4*)x_lds)[tid] = v;
        }
        __syncthreads();
#pragma unroll
        for (int icc = 0; icc < 4; ++icc) {
            float xv[32];
#pragma unroll
            for (int wq = 0; wq < 8; ++wq)
                *(float4*)(xv + 4 * wq) = ((const float4*)(x_lds + icc * 88))[tx * 2 + wq];
#pragma unroll
            for (int d = 0; d < DD; ++d) {
                float4 kv = ((const float4*)(k_lds + (icc * DD + d) * 128))[ty];
                float kvv[4] = {kv.x, kv.y, kv.z, kv.w};
#pragma unroll
                for (int ro = 0; ro < 4; ++ro)
#pragma unroll
                    for (int rt = 0; rt < 8; ++rt)
                        acc[ro][rt] += kvv[ro] * xv[rt + d];
            }
        }
    }
    const int tvalid = TOUT - t0;
#pragma unroll
    for (int ro = 0; ro < 4; ++ro) {
        float* op = out + (size_t)(b * O + o0 + ty * 4 + ro) * TOUT + t0;
#pragma unroll
        for (int u = 0; u < 2; ++u) {
            int toff = tx * 8 + u * 4;
            if (toff < tvalid) {
                float4 v = make_float4(acc[ro][u * 4 + 0], acc[ro][u * 4 + 1],
                                       acc[ro][u * 4 + 2], acc[ro][u * 4 + 3]);
                *(float4*)(op + toff) = v;
            }
        }
    }
}

__global__ void bn_stats(const float* __restrict__ cinh, const float* __restrict__ gamma,
                         const float* __restrict__ beta, float* __restrict__ scale,
                         float* __restrict__ shift) {
    const int c = blockIdx.x, tid = threadIdx.x;
    float sum = 0.f, sq = 0.f;
    for (int idx = tid; idx < BB * TOUT; idx += 256) {
        int b = idx / TOUT, t = idx - b * TOUT;
        float v = cinh[(size_t)(b * OINH + c) * TOUT + t];
        sum += v; sq += v * v;
    }
#pragma unroll
    for (int off = 32; off; off >>= 1) {
        sum += __shfl_down(sum, off);
        sq  += __shfl_down(sq, off);
    }
    __shared__ float ls[8];
    int wid = tid >> 6;
    if ((tid & 63) == 0) { ls[wid * 2] = sum; ls[wid * 2 + 1] = sq; }
    __syncthreads();
    if (tid == 0) {
        float S = 0.f, Q = 0.f;
#pragma unroll
        for (int wv = 0; wv < 4; ++wv) { S += ls[wv * 2]; Q += ls[wv * 2 + 1]; }
        const float n = (float)(BB * TOUT);
        float mean = S / n;
        float var  = Q / n - mean * mean;
        float rs   = 1.f / sqrtf(var + 1e-5f);
        float sc   = gamma[c] * rs;
        scale[c] = sc;
        shift[c] = beta[c] - mean * sc;
    }
}

__global__ void lif_kernel(const float* __restrict__ cinh, const float* __restrict__ scale,
                           const float* __restrict__ shift, unsigned char* __restrict__ spk) {
    const int b = blockIdx.x, c = threadIdx.x;
    const float sc = scale[c], sh = shift[c];
    const float* row = cinh + (size_t)(b * OINH + c) * TOUT;
    float v = 0.f;
    for (int t = 0; t < TOUT; ++t) {
        float xin = row[t] * sc + sh;
        v = 0.5f * v + xin;
        unsigned char s = (v >= 1.f) ? 1 : 0;
        spk[((size_t)t * BB + b) * OINH + c] = s;
        v = (v >= 1.f) ? 0.f : v;
    }
}

__global__ __launch_bounds__(256)
void finale(const unsigned char* __restrict__ spk, const float* __restrict__ wt,
            float* __restrict__ out) {
    __shared__ float s_lds[64 * 129];
    const int tid = threadIdx.x;
    const int tx = tid & 15, ty = tid >> 4;
    const int b = blockIdx.z, t0 = blockIdx.x * 64, o0 = blockIdx.y * 64;

#pragma unroll
    for (int s = 0; s < 32; ++s) {
        int f = tid + s * 256;
        int tt = f >> 7, c = f & 127;
        float v = 0.f;
        if (t0 + tt < TOUT) v = (float)spk[((size_t)(t0 + tt) * BB + b) * OINH + c];
        s_lds[tt * 129 + c] = v;
    }
    __syncthreads();

    float acc[4][4] = {{0.f}};
#pragma unroll 4
    for (int c = 0; c < 128; ++c) {
        float4 wv = *(const float4*)(wt + c * OEXC + o0 + ty * 4);
        float wvv[4] = {wv.x, wv.y, wv.z, wv.w};
        float sv[4];
#pragma unroll
        for (int rt = 0; rt < 4; ++rt) sv[rt] = s_lds[(tx * 4 + rt) * 129 + c];
#pragma unroll
        for (int ro = 0; ro < 4; ++ro)
#pragma unroll
            for (int rt = 0; rt < 4; ++rt)
                acc[ro][rt] += wvv[ro] * sv[rt];
    }

    const int tvalid = TOUT - t0;
    if (tx * 4 < tvalid) {
#pragma unroll
        for (int ro = 0; ro < 4; ++ro) {
            float* op = out + (size_t)(b * OEXC + o0 + ty * 4 + ro) * TOUT + t0 + tx * 4;
            float4 v = *(float4*)op;
            v.x += acc[ro][0]; v.y += acc[ro][1]; v.z += acc[ro][2]; v.w += acc[ro][3];
            *(float4*)op = v;
        }
    }
}

// ---------------------------------------------------------------------------
extern "C" void kernel_launch(void* const* d_in, const int* in_sizes, int n_in,
                              void* d_out, int out_size, void* d_ws, size_t ws_size,
                              hipStream_t stream) {
    const float* x       = (const float*)d_in[0];
    const float* W_inh   = (const float*)d_in[1];
    const float* P_inh   = (const float*)d_in[2];
    const float* SIG_inh = (const float*)d_in[3];
    const float* W_exc   = (const float*)d_in[4];
    const float* P_exc   = (const float*)d_in[5];
    const float* SIG_exc = (const float*)d_in[6];
    const float* w_ei    = (const float*)d_in[7];
    const float* gamma   = (const float*)d_in[8];
    const float* beta    = (const float*)d_in[9];
    float* out = (float*)d_out;

    const size_t XT_ELEMS   = (size_t)BB * TROWS * IPAD;
    const size_t KEXC_ELEMS = (size_t)DD * OEXC * IPAD;
    const size_t KINH_ELEMS = (size_t)DD * OINH * IPAD;
    const size_t CINH_ELEMS = (size_t)BB * OINH * TOUT;
    const size_t PEXC_ELEMS = (size_t)BB * OEXC * TOUT;

    const size_t NEED_FAST = 2 * XT_ELEMS * 2 + KEXC_ELEMS * 2 + 2 * KINH_ELEMS * 2 +
                             CINH_ELEMS * 4 + OINH * OEXC * 4 + CINH_ELEMS;
    const size_t NEED_FAST2 = (2 * XT_ELEMS + KEXC_ELEMS + 2 * KINH_ELEMS) * 2 +
                              (PEXC_ELEMS + 2 * CINH_ELEMS + OINH * OEXC + 256) * 4 +
                              CINH_ELEMS;

    if (ws_size >= NEED_FAST2) {
        unsigned short* xTh = (unsigned short*)d_ws;
        unsigned short* xTl = xTh + XT_ELEMS;
        unsigned short* kb2 = xTl + XT_ELEMS;
        unsigned short* kbh = kb2 + KEXC_ELEMS;
        unsigned short* kbl = kbh + KINH_ELEMS;
        float* pexc1 = (float*)(kbl + KINH_ELEMS);
        float* cinh  = pexc1 + PEXC_ELEMS;
        float* pinh1 = cinh + CINH_ELEMS;
        float* wt    = pinh1 + CINH_ELEMS;
        float* scale = wt + OINH * OEXC;
        float* shift = scale + OINH;
        unsigned char* spk = (unsigned char*)(shift + OINH);

        hipLaunchKernelGGL(kexc_build, dim3((OEXC * IPAD + 255) / 256), dim3(256), 0, stream,
                           W_exc, P_exc, SIG_exc, kb2);
        hipLaunchKernelGGL(kinh_build, dim3((OINH * IPAD + 255) / 256), dim3(256), 0, stream,
                           W_inh, P_inh, SIG_inh, kbh, kbl);
        hipLaunchKernelGGL(xt_kernel, dim3(5, 11, 64), dim3(256), 0, stream, x, xTh, xTl);
        hipLaunchKernelGGL(wt_kernel, dim3(128), dim3(256), 0, stream, w_ei, wt);

        hipLaunchKernelGGL(conv_fused_v7, dim3(6, 4, 32), dim3(256), 0, stream,
                           xTh, xTl, kb2, kbh, kbl, out, pexc1, cinh, pinh1);

        hipLaunchKernelGGL(add_exc, dim3((unsigned)(PEXC_ELEMS / 4 / 256)), dim3(256), 0, stream,
                           pexc1, out);
        hipLaunchKernelGGL(bn_stats2, dim3(128), dim3(256), 0, stream,
                           cinh, pinh1, gamma, beta, scale, shift);
        hipLaunchKernelGGL(lif2, dim3(64), dim3(128), 0, stream, cinh, scale, shift, spk);
        hipLaunchKernelGGL(finale, dim3(5, 4, 64), dim3(256), 0, stream, spk, wt, out);
    } else if (ws_size >= NEED_FAST) {
        unsigned short* xTh = (unsigned short*)d_ws;
        unsigned short* xTl = xTh + XT_ELEMS;
        unsigned short* kb2 = xTl + XT_ELEMS;
        unsigned short* kbh = kb2 + KEXC_ELEMS;
        unsigned short* kbl = kbh + KINH_ELEMS;
        float* cinh  = (float*)(kbl + KINH_ELEMS);
        float* wt    = cinh + CINH_ELEMS;
        float* scale = wt + OINH * OEXC;
        float* shift = scale + OINH;
        unsigned char* spk = (unsigned char*)(shift + OINH);

        hipLaunchKernelGGL(kexc_build, dim3((OEXC * IPAD + 255) / 256), dim3(256), 0, stream,
                           W_exc, P_exc, SIG_exc, kb2);
        hipLaunchKernelGGL(kinh_build, dim3((OINH * IPAD + 255) / 256), dim3(256), 0, stream,
                           W_inh, P_inh, SIG_inh, kbh, kbl);
        hipLaunchKernelGGL(xt_kernel, dim3(5, 11, 64), dim3(256), 0, stream, x, xTh, xTl);
        hipLaunchKernelGGL(wt_kernel, dim3(128), dim3(256), 0, stream, w_ei, wt);

        hipLaunchKernelGGL(conv_mfma, dim3(3, 2, 64), dim3(128), 0, stream, xTh, kb2, out);
        hipLaunchKernelGGL(conv_mfma_inh, dim3(3, 2, 64), dim3(128), 0, stream,
                           xTh, xTl, kbh, kbl, cinh);

        hipLaunchKernelGGL(bn_stats, dim3(128), dim3(256), 0, stream, cinh, gamma, beta, scale, shift);
        hipLaunchKernelGGL(lif_kernel, dim3(64), dim3(128), 0, stream, cinh, scale, shift, spk);
        hipLaunchKernelGGL(finale, dim3(5, 4, 64), dim3(256), 0, stream, spk, wt, out);
    } else {
        unsigned short* xTh = (unsigned short*)d_ws;
        unsigned short* kb2 = xTh + XT_ELEMS;
        float* kt_inh = (float*)(kb2 + KEXC_ELEMS);
        float* cinh   = kt_inh + 2240000;
        float* wt     = cinh + CINH_ELEMS;
        float* scale  = wt + OINH * OEXC;
        float* shift  = scale + OINH;
        unsigned char* spk = (unsigned char*)(shift + OINH);

        hipLaunchKernelGGL(kexc_build, dim3((OEXC * IPAD + 255) / 256), dim3(256), 0, stream,
                           W_exc, P_exc, SIG_exc, kb2);
        hipLaunchKernelGGL(build_kt, dim3(350), dim3(256), 0, stream,
                           W_inh, P_inh, SIG_inh, kt_inh, OINH);
        hipLaunchKernelGGL(xt_kernel, dim3(5, 11, 64), dim3(256), 0, stream, x, xTh,
                           (unsigned short*)nullptr);
        hipLaunchKernelGGL(wt_kernel, dim3(128), dim3(256), 0, stream, w_ei, wt);

        hipLaunchKernelGGL(conv_mfma, dim3(3, 2, 64), dim3(128), 0, stream, xTh, kb2, out);
        hipLaunchKernelGGL(conv_dcls_fb, dim3(5, 1, 64), dim3(256), 0, stream, x, kt_inh, cinh, OINH);

        hipLaunchKernelGGL(bn_stats, dim3(128), dim3(256), 0, stream, cinh, gamma, beta, scale, shift);
        hipLaunchKernelGGL(lif_kernel, dim3(64), dim3(128), 0, stream, cinh, scale, shift, spk);
        hipLaunchKernelGGL(finale, dim3(5, 4, 64), dim3(256), 0, stream, spk, wt, out);
    }
}